// Round 1
// baseline (2596.462 us; speedup 1.0000x reference)
//
#include <hip/hip_runtime.h>
#include <cstdint>
#include <cstddef>

#define NTOK 8192
#define CDIM 1024
#define NEXP 8
#define HDIM 2730
#define HP   2816

typedef unsigned short u16;
typedef __attribute__((ext_vector_type(4))) float f32x4;
typedef __attribute__((ext_vector_type(8))) __bf16 bf16x8;
typedef __attribute__((ext_vector_type(4))) unsigned short u16x4;

static __device__ __forceinline__ u16 f2bf(float f) {
  __bf16 h = (__bf16)f;
  return __builtin_bit_cast(u16, h);
}

// 16B-per-lane async global->LDS. LDS dest must be wave-uniform base; lane i's
// 16B lands at base + i*16 (guide §5, m97/m104). CK-style addrspace cast idiom.
static __device__ __forceinline__ void async_cp16(const void* gsrc, void* ldst) {
  auto g = reinterpret_cast<const __attribute__((address_space(1))) unsigned int*>(
      reinterpret_cast<uintptr_t>(gsrc));
  auto l = reinterpret_cast<__attribute__((address_space(3))) unsigned int*>(
      static_cast<unsigned int>(reinterpret_cast<uintptr_t>(ldst)));
  __builtin_amdgcn_global_load_lds(g, l, 16, 0, 0);
}

static __device__ __forceinline__ f32x4 mfma16(bf16x8 a, bf16x8 b, f32x4 c) {
  return __builtin_amdgcn_mfma_f32_16x16x32_bf16(a, b, c, 0, 0, 0);
}

// ---------------- x fp32 -> bf16 ----------------
__global__ void convert_x_kernel(const float* __restrict__ x, u16* __restrict__ xb) {
  size_t i = (size_t)blockIdx.x * blockDim.x + threadIdx.x;
  f32x4 v = ((const f32x4*)x)[i];
  u16x4 o;
  o.x = f2bf(v.x); o.y = f2bf(v.y); o.z = f2bf(v.z); o.w = f2bf(v.w);
  ((u16x4*)xb)[i] = o;
}

// ---------------- router: wave per token ----------------
__global__ void router_kernel(const float* __restrict__ x, const float* __restrict__ gw,
                              int* __restrict__ idx_top, float* __restrict__ w_top,
                              int* __restrict__ perm_sh, float* __restrict__ scl_sh,
                              int* __restrict__ counts, float* __restrict__ sumP) {
  __shared__ float gws[CDIM * NEXP];
  for (int i = threadIdx.x; i < CDIM * NEXP; i += 256) gws[i] = gw[i];
  __syncthreads();
  const int lane = threadIdx.x & 63;
  const int wave = threadIdx.x >> 6;
  const int t = blockIdx.x * 4 + wave;
  float acc[NEXP];
#pragma unroll
  for (int e = 0; e < NEXP; ++e) acc[e] = 0.f;
  const float* xr = x + (size_t)t * CDIM;
#pragma unroll
  for (int u = 0; u < CDIM / 64; ++u) {
    float xv = xr[lane + 64 * u];
    const float* gr = &gws[(lane + 64 * u) * NEXP];
#pragma unroll
    for (int e = 0; e < NEXP; ++e) acc[e] = fmaf(xv, gr[e], acc[e]);
  }
#pragma unroll
  for (int e = 0; e < NEXP; ++e) {
    float v = acc[e];
#pragma unroll
    for (int s = 32; s > 0; s >>= 1) v += __shfl_xor(v, s, 64);
    acc[e] = v;
  }
  if (lane == 0) {
    float mx = acc[0];
#pragma unroll
    for (int e = 1; e < NEXP; ++e) mx = fmaxf(mx, acc[e]);
    float p[NEXP], s = 0.f;
#pragma unroll
    for (int e = 0; e < NEXP; ++e) { p[e] = __expf(acc[e] - mx); s += p[e]; }
    float inv = 1.f / s;
#pragma unroll
    for (int e = 0; e < NEXP; ++e) p[e] *= inv;
    int i1 = 0;
#pragma unroll
    for (int e = 1; e < NEXP; ++e) if (p[e] > p[i1]) i1 = e;
    int i2 = (i1 == 0) ? 1 : 0;
#pragma unroll
    for (int e = 0; e < NEXP; ++e)
      if (e != i1 && e != i2 && p[e] > p[i2]) i2 = e;
    float wsum = p[i1] + p[i2];
    idx_top[t * 2] = i1; idx_top[t * 2 + 1] = i2;
    w_top[t * 2] = p[i1] / wsum; w_top[t * 2 + 1] = p[i2] / wsum;
    atomicAdd(&counts[i1], 1); atomicAdd(&counts[i2], 1);
#pragma unroll
    for (int e = 0; e < NEXP; ++e) atomicAdd(&sumP[e], p[e]);
    perm_sh[t] = t; scl_sh[t] = 1.0f;  // shared-expert identity list
  }
}

// ---------------- offsets + aux loss ----------------
__global__ void offsets_aux_kernel(int* __restrict__ counts, const float* __restrict__ sumP,
                                   int* __restrict__ offs, float* __restrict__ aux_out) {
  if (threadIdx.x == 0 && blockIdx.x == 0) {
    int o = 0;
    float aux = 0.f;
    for (int e = 0; e < NEXP; ++e) {
      offs[e] = o; o += counts[e];
      aux += ((float)counts[e] / (float)NTOK) * (sumP[e] / (float)NTOK);
    }
    offs[NEXP] = o;        // == 2*NTOK
    counts[NEXP] = NTOK;   // shared expert token count
    aux_out[0] = (float)NEXP * aux;
  }
}

// ---------------- scatter: build per-expert token lists ----------------
__global__ void scatter_kernel(const int* __restrict__ idx_top, const float* __restrict__ w_top,
                               const int* __restrict__ offs, int* __restrict__ cursor,
                               int* __restrict__ perm, float* __restrict__ scl) {
  int t = blockIdx.x * 256 + threadIdx.x;
#pragma unroll
  for (int k = 0; k < 2; ++k) {
    int e = idx_top[t * 2 + k];
    int pos = atomicAdd(&cursor[e], 1);
    int o = offs[e] + pos;
    perm[o] = t;
    scl[o] = w_top[t * 2 + k];
  }
}

// ------- fp32 [K][M] -> bf16 [Mp][Kp] transpose+pad (zero padding) -------
__global__ void convt_kernel(const float* __restrict__ src, u16* __restrict__ dst,
                             int K, int M, int Kp, int Mp) {
  __shared__ float tile[32][33];
  int sk = blockIdx.x * 32, sm = blockIdx.y * 32;
  int tx = threadIdx.x & 31, ty = threadIdx.x >> 5;
#pragma unroll
  for (int i = 0; i < 4; ++i) {
    int k = sk + ty + i * 8, m = sm + tx;
    tile[ty + i * 8][tx] = (k < K && m < M) ? src[(size_t)k * M + m] : 0.f;
  }
  __syncthreads();
#pragma unroll
  for (int i = 0; i < 4; ++i) {
    int m = sm + ty + i * 8, k = sk + tx;
    dst[(size_t)m * Kp + k] = f2bf(tile[tx][ty + i * 8]);
  }
}

// ------- fused dual GEMM + SwiGLU: g = silu(x@w1) * (x@w2), gathered rows -------
// BM=128, BN=64, BK=32; 4 waves as 2x2 (wave: 64 rows x 32 cols), dual accum.
__global__ __launch_bounds__(256) void gemm_h_kernel(
    const u16* __restrict__ xb, const u16* __restrict__ B1, const u16* __restrict__ B2,
    u16* __restrict__ g, const int* __restrict__ perm, const int* __restrict__ offs,
    const int* __restrict__ counts, int e) {
  const int Te = counts[e];
  const int m0 = blockIdx.x * 128;
  if (m0 >= Te) return;
  const int* pl = perm + offs[e];
  const int n0 = blockIdx.y * 64;

  __shared__ __align__(16) u16 As[128 * 32];
  __shared__ __align__(16) u16 Bs1[64 * 32];
  __shared__ __align__(16) u16 Bs2[64 * 32];

  const int lane = threadIdx.x & 63;
  const int wave = threadIdx.x >> 6;
  const int wr = wave >> 1, wc = wave & 1;
  const int sr = lane >> 2, sc = lane & 3;

  int r0 = m0 + wave * 16 + sr;      if (r0 >= Te) r0 = Te - 1;
  int r1 = m0 + 64 + wave * 16 + sr; if (r1 >= Te) r1 = Te - 1;
  const u16* ga0 = xb + (size_t)pl[r0] * CDIM + sc * 8;
  const u16* ga1 = xb + (size_t)pl[r1] * CDIM + sc * 8;
  const u16* gb1 = B1 + (size_t)(n0 + wave * 16 + sr) * CDIM + sc * 8;
  const u16* gb2 = B2 + (size_t)(n0 + wave * 16 + sr) * CDIM + sc * 8;
  u16* la0 = &As[(wave * 16) * 32];
  u16* la1 = &As[(64 + wave * 16) * 32];
  u16* lb1 = &Bs1[(wave * 16) * 32];
  u16* lb2 = &Bs2[(wave * 16) * 32];

  const int fr = lane & 15, fs = lane >> 4;
  int aoff[4], boff[2];
#pragma unroll
  for (int i = 0; i < 4; ++i) aoff[i] = (wr * 64 + i * 16 + fr) * 32 + fs * 8;
#pragma unroll
  for (int j = 0; j < 2; ++j) boff[j] = (wc * 32 + j * 16 + fr) * 32 + fs * 8;

  f32x4 acc1[4][2] = {};
  f32x4 acc2[4][2] = {};

  for (int k0 = 0; k0 < CDIM; k0 += 32) {
    async_cp16(ga0, la0);
    async_cp16(ga1, la1);
    async_cp16(gb1, lb1);
    async_cp16(gb2, lb2);
    ga0 += 32; ga1 += 32; gb1 += 32; gb2 += 32;
    __syncthreads();
    bf16x8 a[4], b1[2], b2[2];
#pragma unroll
    for (int i = 0; i < 4; ++i) a[i] = *(const bf16x8*)&As[aoff[i]];
#pragma unroll
    for (int j = 0; j < 2; ++j) {
      b1[j] = *(const bf16x8*)&Bs1[boff[j]];
      b2[j] = *(const bf16x8*)&Bs2[boff[j]];
    }
#pragma unroll
    for (int i = 0; i < 4; ++i)
#pragma unroll
      for (int j = 0; j < 2; ++j) {
        acc1[i][j] = mfma16(a[i], b1[j], acc1[i][j]);
        acc2[i][j] = mfma16(a[i], b2[j], acc2[i][j]);
      }
    __syncthreads();
  }

  // epilogue: silu(h1)*h2 -> bf16 g.  C/D layout: col=lane&15, row=quad*4+reg.
#pragma unroll
  for (int i = 0; i < 4; ++i)
#pragma unroll
    for (int j = 0; j < 2; ++j)
#pragma unroll
      for (int r = 0; r < 4; ++r) {
        int m = wr * 64 + i * 16 + fs * 4 + r;
        int col = n0 + wc * 32 + j * 16 + fr;
        float h1 = acc1[i][j][r];
        float h2 = acc2[i][j][r];
        float gv = h1 / (1.f + __expf(-h1)) * h2;
        g[(size_t)(m0 + m) * HP + col] = f2bf(gv);
      }
}

// ------- GEMM: y = g @ w3, scatter out[perm[row]] (+)= scale*y -------
__global__ __launch_bounds__(256) void gemm_out_kernel(
    const u16* __restrict__ g, const u16* __restrict__ B3, float* __restrict__ out,
    const int* __restrict__ perm, const float* __restrict__ scl,
    const int* __restrict__ offs, const int* __restrict__ counts, int e, int init) {
  const int Te = counts[e];
  const int m0 = blockIdx.x * 128;
  if (m0 >= Te) return;
  const int lbase = offs[e];
  const int n0 = blockIdx.y * 64;

  __shared__ __align__(16) u16 As[128 * 32];
  __shared__ __align__(16) u16 Bs[64 * 32];

  const int lane = threadIdx.x & 63;
  const int wave = threadIdx.x >> 6;
  const int wr = wave >> 1, wc = wave & 1;
  const int sr = lane >> 2, sc = lane & 3;

  const u16* ga0 = g + (size_t)(m0 + wave * 16 + sr) * HP + sc * 8;
  const u16* ga1 = g + (size_t)(m0 + 64 + wave * 16 + sr) * HP + sc * 8;
  const u16* gb  = B3 + (size_t)(n0 + wave * 16 + sr) * HP + sc * 8;
  u16* la0 = &As[(wave * 16) * 32];
  u16* la1 = &As[(64 + wave * 16) * 32];
  u16* lb  = &Bs[(wave * 16) * 32];

  const int fr = lane & 15, fs = lane >> 4;
  int aoff[4], boff[2];
#pragma unroll
  for (int i = 0; i < 4; ++i) aoff[i] = (wr * 64 + i * 16 + fr) * 32 + fs * 8;
#pragma unroll
  for (int j = 0; j < 2; ++j) boff[j] = (wc * 32 + j * 16 + fr) * 32 + fs * 8;

  f32x4 acc[4][2] = {};

  for (int k0 = 0; k0 < HP; k0 += 32) {
    async_cp16(ga0, la0);
    async_cp16(ga1, la1);
    async_cp16(gb, lb);
    ga0 += 32; ga1 += 32; gb += 32;
    __syncthreads();
    bf16x8 a[4], b[2];
#pragma unroll
    for (int i = 0; i < 4; ++i) a[i] = *(const bf16x8*)&As[aoff[i]];
#pragma unroll
    for (int j = 0; j < 2; ++j) b[j] = *(const bf16x8*)&Bs[boff[j]];
#pragma unroll
    for (int i = 0; i < 4; ++i)
#pragma unroll
      for (int j = 0; j < 2; ++j)
        acc[i][j] = mfma16(a[i], b[j], acc[i][j]);
    __syncthreads();
  }

#pragma unroll
  for (int i = 0; i < 4; ++i) {
#pragma unroll
    for (int r = 0; r < 4; ++r) {
      int m = wr * 64 + i * 16 + fs * 4 + r;
      int grow = m0 + m;
      if (grow < Te) {
        int slot = lbase + grow;
        int tok = perm[slot];
        float s = scl[slot];
#pragma unroll
        for (int j = 0; j < 2; ++j) {
          int col = n0 + wc * 32 + j * 16 + fr;
          size_t oi = (size_t)tok * CDIM + col;
          float v = s * acc[i][j][r];
          if (init) out[oi] = v;
          else out[oi] += v;
        }
      }
    }
  }
}

extern "C" void kernel_launch(void* const* d_in, const int* in_sizes, int n_in,
                              void* d_out, int out_size, void* d_ws, size_t ws_size,
                              hipStream_t stream) {
  (void)in_sizes; (void)n_in; (void)out_size; (void)ws_size;
  const float* x   = (const float*)d_in[0];
  const float* gw  = (const float*)d_in[1];
  const float* w1  = (const float*)d_in[2];
  const float* w2  = (const float*)d_in[3];
  const float* w3  = (const float*)d_in[4];
  const float* sw1 = (const float*)d_in[5];
  const float* sw2 = (const float*)d_in[6];
  const float* sw3 = (const float*)d_in[7];
  float* out = (float*)d_out;

  char* p = (char*)d_ws;
  auto alloc = [&](size_t b) { char* r = p; p += (b + 255) & ~(size_t)255; return r; };
  u16*   xb      = (u16*)alloc((size_t)NTOK * CDIM * 2);
  u16*   wT1     = (u16*)alloc((size_t)HP * CDIM * 2);
  u16*   wT2     = (u16*)alloc((size_t)HP * CDIM * 2);
  u16*   wT3     = (u16*)alloc((size_t)CDIM * HP * 2);
  u16*   gbuf    = (u16*)alloc((size_t)NTOK * HP * 2);
  int*   idx_top = (int*)alloc((size_t)NTOK * 2 * 4);
  float* w_top   = (float*)alloc((size_t)NTOK * 2 * 4);
  int*   perm    = (int*)alloc((size_t)NTOK * 3 * 4);
  float* scl     = (float*)alloc((size_t)NTOK * 3 * 4);
  int*   ctrl    = (int*)alloc(256);
  int*   counts  = ctrl;                 // [0..8]
  int*   cursor  = ctrl + 12;            // [0..7]
  float* sumP    = (float*)(ctrl + 20);  // [0..7]
  int*   offs    = ctrl + 28;            // [0..8]

  hipMemsetAsync(ctrl, 0, 256, stream);
  convert_x_kernel<<<NTOK * CDIM / 4 / 256, 256, 0, stream>>>(x, xb);
  router_kernel<<<NTOK / 4, 256, 0, stream>>>(x, gw, idx_top, w_top,
                                              perm + 2 * NTOK, scl + 2 * NTOK, counts, sumP);
  offsets_aux_kernel<<<1, 64, 0, stream>>>(counts, sumP, offs, out + (size_t)NTOK * CDIM);
  scatter_kernel<<<NTOK / 256, 256, 0, stream>>>(idx_top, w_top, offs, cursor, perm, scl);

  // shared expert first (init-writes every out element), then routed 0..7
  for (int ei = 0; ei < 9; ++ei) {
    int e = (ei == 0) ? NEXP : ei - 1;
    const float* a1 = (e == NEXP) ? sw1 : w1 + (size_t)e * CDIM * HDIM;
    const float* a2 = (e == NEXP) ? sw2 : w2 + (size_t)e * CDIM * HDIM;
    const float* a3 = (e == NEXP) ? sw3 : w3 + (size_t)e * HDIM * CDIM;
    convt_kernel<<<dim3(CDIM / 32, HP / 32), 256, 0, stream>>>(a1, wT1, CDIM, HDIM, CDIM, HP);
    convt_kernel<<<dim3(CDIM / 32, HP / 32), 256, 0, stream>>>(a2, wT2, CDIM, HDIM, CDIM, HP);
    convt_kernel<<<dim3(HP / 32, CDIM / 32), 256, 0, stream>>>(a3, wT3, HDIM, CDIM, HP, CDIM);
    gemm_h_kernel<<<dim3(NTOK / 128, HP / 64), 256, 0, stream>>>(
        xb, wT1, wT2, gbuf, perm, offs, counts, e);
    gemm_out_kernel<<<dim3(NTOK / 128, CDIM / 64), 256, 0, stream>>>(
        gbuf, wT3, out, perm, scl, offs, counts, e, (e == NEXP) ? 1 : 0);
  }
}

// Round 2
// 1688.154 us; speedup vs baseline: 1.5380x; 1.5380x over previous
//
#include <hip/hip_runtime.h>
#include <cstdint>
#include <cstddef>

#define NTOK 8192
#define CDIM 1024
#define NEXP 8
#define HDIM 2730
#define HP   2816

typedef unsigned short u16;
typedef __attribute__((ext_vector_type(4))) float f32x4;
typedef __attribute__((ext_vector_type(8))) __bf16 bf16x8;
typedef __attribute__((ext_vector_type(4))) unsigned short u16x4;

static __device__ __forceinline__ u16 f2bf(float f) {
  __bf16 h = (__bf16)f;
  return __builtin_bit_cast(u16, h);
}

// 16B-per-lane async global->LDS. LDS dest must be wave-uniform base; lane i's
// 16B lands at base + i*16 (guide §5, m97/m104).
static __device__ __forceinline__ void async_cp16(const void* gsrc, void* ldst) {
  auto g = reinterpret_cast<const __attribute__((address_space(1))) unsigned int*>(
      reinterpret_cast<uintptr_t>(gsrc));
  auto l = reinterpret_cast<__attribute__((address_space(3))) unsigned int*>(
      static_cast<unsigned int>(reinterpret_cast<uintptr_t>(ldst)));
  __builtin_amdgcn_global_load_lds(g, l, 16, 0, 0);
}

static __device__ __forceinline__ f32x4 mfma16(bf16x8 a, bf16x8 b, f32x4 c) {
  return __builtin_amdgcn_mfma_f32_16x16x32_bf16(a, b, c, 0, 0, 0);
}

// ---------------- x fp32 -> bf16 ----------------
__global__ void convert_x_kernel(const float* __restrict__ x, u16* __restrict__ xb) {
  size_t i = (size_t)blockIdx.x * blockDim.x + threadIdx.x;
  f32x4 v = ((const f32x4*)x)[i];
  u16x4 o;
  o.x = f2bf(v.x); o.y = f2bf(v.y); o.z = f2bf(v.z); o.w = f2bf(v.w);
  ((u16x4*)xb)[i] = o;
}

// ---------------- router: wave per token, NO atomics ----------------
__global__ void router_kernel(const float* __restrict__ x, const float* __restrict__ gw,
                              int* __restrict__ idx_top, float* __restrict__ w_top,
                              float* __restrict__ probs,
                              int* __restrict__ perm_sh, float* __restrict__ scl_sh) {
  // gate stored transposed [E][C]: lane stride 4B -> conflict-free LDS reads
  __shared__ float gws[NEXP][CDIM];
  for (int i = threadIdx.x; i < CDIM * NEXP; i += 256) {
    int c = i >> 3, e = i & 7;
    gws[e][c] = gw[i];
  }
  __syncthreads();
  const int lane = threadIdx.x & 63;
  const int wave = threadIdx.x >> 6;
  const int t = blockIdx.x * 4 + wave;
  float acc[NEXP];
#pragma unroll
  for (int e = 0; e < NEXP; ++e) acc[e] = 0.f;
  const float* xr = x + (size_t)t * CDIM;
#pragma unroll
  for (int u = 0; u < CDIM / 64; ++u) {
    float xv = xr[lane + 64 * u];
#pragma unroll
    for (int e = 0; e < NEXP; ++e) acc[e] = fmaf(xv, gws[e][lane + 64 * u], acc[e]);
  }
#pragma unroll
  for (int e = 0; e < NEXP; ++e) {
    float v = acc[e];
#pragma unroll
    for (int s = 32; s > 0; s >>= 1) v += __shfl_xor(v, s, 64);
    acc[e] = v;
  }
  if (lane == 0) {
    float mx = acc[0];
#pragma unroll
    for (int e = 1; e < NEXP; ++e) mx = fmaxf(mx, acc[e]);
    float p[NEXP], s = 0.f;
#pragma unroll
    for (int e = 0; e < NEXP; ++e) { p[e] = __expf(acc[e] - mx); s += p[e]; }
    float inv = 1.f / s;
#pragma unroll
    for (int e = 0; e < NEXP; ++e) { p[e] *= inv; probs[t * NEXP + e] = p[e]; }
    int i1 = 0;
#pragma unroll
    for (int e = 1; e < NEXP; ++e) if (p[e] > p[i1]) i1 = e;
    int i2 = (i1 == 0) ? 1 : 0;
#pragma unroll
    for (int e = 0; e < NEXP; ++e)
      if (e != i1 && e != i2 && p[e] > p[i2]) i2 = e;
    float wsum = p[i1] + p[i2];
    idx_top[t * 2] = i1; idx_top[t * 2 + 1] = i2;
    w_top[t * 2] = p[i1] / wsum; w_top[t * 2 + 1] = p[i2] / wsum;
    perm_sh[t] = t; scl_sh[t] = 1.0f;  // shared-expert identity list
  }
}

// ---------------- single-block reduction: counts, offsets, aux ----------------
__global__ void reduce_aux_kernel(const float* __restrict__ probs,
                                  const int* __restrict__ idx_top,
                                  int* __restrict__ counts, int* __restrict__ offs,
                                  float* __restrict__ aux_out) {
  __shared__ float sP[NEXP];
  __shared__ int sC[NEXP];
  if (threadIdx.x < NEXP) { sP[threadIdx.x] = 0.f; sC[threadIdx.x] = 0; }
  __syncthreads();
  float sp[NEXP];
  int cnt[NEXP];
#pragma unroll
  for (int e = 0; e < NEXP; ++e) { sp[e] = 0.f; cnt[e] = 0; }
  for (int t = threadIdx.x; t < NTOK; t += 256) {
    const float* pr = probs + (size_t)t * NEXP;
    int i1 = idx_top[2 * t], i2 = idx_top[2 * t + 1];
#pragma unroll
    for (int e = 0; e < NEXP; ++e) {
      sp[e] += pr[e];
      cnt[e] += (i1 == e) + (i2 == e);
    }
  }
#pragma unroll
  for (int e = 0; e < NEXP; ++e) {
    float v = sp[e]; int c = cnt[e];
#pragma unroll
    for (int s = 32; s > 0; s >>= 1) { v += __shfl_xor(v, s, 64); c += __shfl_xor(c, s, 64); }
    if ((threadIdx.x & 63) == 0) { atomicAdd(&sP[e], v); atomicAdd(&sC[e], c); }
  }
  __syncthreads();
  if (threadIdx.x == 0) {
    int o = 0; float aux = 0.f;
    for (int e = 0; e < NEXP; ++e) {
      offs[e] = o; counts[e] = sC[e]; o += sC[e];
      aux += ((float)sC[e] / (float)NTOK) * (sP[e] / (float)NTOK);
    }
    offs[NEXP] = o;
    counts[NEXP] = NTOK;   // shared expert token count
    aux_out[0] = (float)NEXP * aux;
  }
}

// ------ scatter: block-aggregated atomics (256 global atomics total) ------
__global__ void scatter_kernel(const int* __restrict__ idx_top, const float* __restrict__ w_top,
                               const int* __restrict__ offs, int* __restrict__ cursor,
                               int* __restrict__ perm, float* __restrict__ scl) {
  __shared__ int lcnt[NEXP], lbase[NEXP], lcur[NEXP];
  if (threadIdx.x < NEXP) { lcnt[threadIdx.x] = 0; lcur[threadIdx.x] = 0; }
  __syncthreads();
  int t = blockIdx.x * 256 + threadIdx.x;
  int e0 = idx_top[2 * t], e1 = idx_top[2 * t + 1];
  atomicAdd(&lcnt[e0], 1);
  atomicAdd(&lcnt[e1], 1);
  __syncthreads();
  if (threadIdx.x < NEXP)
    lbase[threadIdx.x] = atomicAdd(&cursor[threadIdx.x], lcnt[threadIdx.x]);
  __syncthreads();
  int p0 = atomicAdd(&lcur[e0], 1);
  int o0 = offs[e0] + lbase[e0] + p0;
  perm[o0] = t; scl[o0] = w_top[2 * t];
  int p1 = atomicAdd(&lcur[e1], 1);
  int o1 = offs[e1] + lbase[e1] + p1;
  perm[o1] = t; scl[o1] = w_top[2 * t + 1];
}

// ------- fp32 [K][M] -> bf16 [Mp][Kp] transpose+pad (zero padding) -------
__global__ void convt_kernel(const float* __restrict__ src, u16* __restrict__ dst,
                             int K, int M, int Kp, int Mp) {
  __shared__ float tile[32][33];
  int sk = blockIdx.x * 32, sm = blockIdx.y * 32;
  int tx = threadIdx.x & 31, ty = threadIdx.x >> 5;
#pragma unroll
  for (int i = 0; i < 4; ++i) {
    int k = sk + ty + i * 8, m = sm + tx;
    tile[ty + i * 8][tx] = (k < K && m < M) ? src[(size_t)k * M + m] : 0.f;
  }
  __syncthreads();
#pragma unroll
  for (int i = 0; i < 4; ++i) {
    int m = sm + ty + i * 8, k = sk + tx;
    dst[(size_t)m * Kp + k] = f2bf(tile[tx][ty + i * 8]);
  }
}

// ------- fused dual GEMM + SwiGLU: g = silu(x@w1) * (x@w2), gathered rows -------
__global__ __launch_bounds__(256) void gemm_h_kernel(
    const u16* __restrict__ xb, const u16* __restrict__ B1, const u16* __restrict__ B2,
    u16* __restrict__ g, const int* __restrict__ perm, const int* __restrict__ offs,
    const int* __restrict__ counts, int e) {
  const int Te = counts[e];
  const int m0 = blockIdx.x * 128;
  if (m0 >= Te) return;
  const int* pl = perm + offs[e];
  const int n0 = blockIdx.y * 64;

  __shared__ __align__(16) u16 As[128 * 32];
  __shared__ __align__(16) u16 Bs1[64 * 32];
  __shared__ __align__(16) u16 Bs2[64 * 32];

  const int lane = threadIdx.x & 63;
  const int wave = threadIdx.x >> 6;
  const int wr = wave >> 1, wc = wave & 1;
  const int sr = lane >> 2, sc = lane & 3;

  int r0 = m0 + wave * 16 + sr;      if (r0 >= Te) r0 = Te - 1;
  int r1 = m0 + 64 + wave * 16 + sr; if (r1 >= Te) r1 = Te - 1;
  const u16* ga0 = xb + (size_t)pl[r0] * CDIM + sc * 8;
  const u16* ga1 = xb + (size_t)pl[r1] * CDIM + sc * 8;
  const u16* gb1 = B1 + (size_t)(n0 + wave * 16 + sr) * CDIM + sc * 8;
  const u16* gb2 = B2 + (size_t)(n0 + wave * 16 + sr) * CDIM + sc * 8;
  u16* la0 = &As[(wave * 16) * 32];
  u16* la1 = &As[(64 + wave * 16) * 32];
  u16* lb1 = &Bs1[(wave * 16) * 32];
  u16* lb2 = &Bs2[(wave * 16) * 32];

  const int fr = lane & 15, fs = lane >> 4;
  int aoff[4], boff[2];
#pragma unroll
  for (int i = 0; i < 4; ++i) aoff[i] = (wr * 64 + i * 16 + fr) * 32 + fs * 8;
#pragma unroll
  for (int j = 0; j < 2; ++j) boff[j] = (wc * 32 + j * 16 + fr) * 32 + fs * 8;

  f32x4 acc1[4][2] = {};
  f32x4 acc2[4][2] = {};

  for (int k0 = 0; k0 < CDIM; k0 += 32) {
    async_cp16(ga0, la0);
    async_cp16(ga1, la1);
    async_cp16(gb1, lb1);
    async_cp16(gb2, lb2);
    ga0 += 32; ga1 += 32; gb1 += 32; gb2 += 32;
    __syncthreads();
    bf16x8 a[4], b1[2], b2[2];
#pragma unroll
    for (int i = 0; i < 4; ++i) a[i] = *(const bf16x8*)&As[aoff[i]];
#pragma unroll
    for (int j = 0; j < 2; ++j) {
      b1[j] = *(const bf16x8*)&Bs1[boff[j]];
      b2[j] = *(const bf16x8*)&Bs2[boff[j]];
    }
#pragma unroll
    for (int i = 0; i < 4; ++i)
#pragma unroll
      for (int j = 0; j < 2; ++j) {
        acc1[i][j] = mfma16(a[i], b1[j], acc1[i][j]);
        acc2[i][j] = mfma16(a[i], b2[j], acc2[i][j]);
      }
    __syncthreads();
  }

  // epilogue: silu(h1)*h2 -> bf16 g.  C/D layout: col=lane&15, row=quad*4+reg.
#pragma unroll
  for (int i = 0; i < 4; ++i)
#pragma unroll
    for (int j = 0; j < 2; ++j)
#pragma unroll
      for (int r = 0; r < 4; ++r) {
        int m = wr * 64 + i * 16 + fs * 4 + r;
        int col = n0 + wc * 32 + j * 16 + fr;
        float h1 = acc1[i][j][r];
        float h2 = acc2[i][j][r];
        float gv = h1 / (1.f + __expf(-h1)) * h2;
        g[(size_t)(m0 + m) * HP + col] = f2bf(gv);
      }
}

// ------- GEMM: y = g @ w3, scatter out[perm[row]] (+)= scale*y -------
__global__ __launch_bounds__(256) void gemm_out_kernel(
    const u16* __restrict__ g, const u16* __restrict__ B3, float* __restrict__ out,
    const int* __restrict__ perm, const float* __restrict__ scl,
    const int* __restrict__ offs, const int* __restrict__ counts, int e, int init) {
  const int Te = counts[e];
  const int m0 = blockIdx.x * 128;
  if (m0 >= Te) return;
  const int lbase = offs[e];
  const int n0 = blockIdx.y * 64;

  __shared__ __align__(16) u16 As[128 * 32];
  __shared__ __align__(16) u16 Bs[64 * 32];

  const int lane = threadIdx.x & 63;
  const int wave = threadIdx.x >> 6;
  const int wr = wave >> 1, wc = wave & 1;
  const int sr = lane >> 2, sc = lane & 3;

  const u16* ga0 = g + (size_t)(m0 + wave * 16 + sr) * HP + sc * 8;
  const u16* ga1 = g + (size_t)(m0 + 64 + wave * 16 + sr) * HP + sc * 8;
  const u16* gb  = B3 + (size_t)(n0 + wave * 16 + sr) * HP + sc * 8;
  u16* la0 = &As[(wave * 16) * 32];
  u16* la1 = &As[(64 + wave * 16) * 32];
  u16* lb  = &Bs[(wave * 16) * 32];

  const int fr = lane & 15, fs = lane >> 4;
  int aoff[4], boff[2];
#pragma unroll
  for (int i = 0; i < 4; ++i) aoff[i] = (wr * 64 + i * 16 + fr) * 32 + fs * 8;
#pragma unroll
  for (int j = 0; j < 2; ++j) boff[j] = (wc * 32 + j * 16 + fr) * 32 + fs * 8;

  f32x4 acc[4][2] = {};

  for (int k0 = 0; k0 < HP; k0 += 32) {
    async_cp16(ga0, la0);
    async_cp16(ga1, la1);
    async_cp16(gb, lb);
    ga0 += 32; ga1 += 32; gb += 32;
    __syncthreads();
    bf16x8 a[4], b[2];
#pragma unroll
    for (int i = 0; i < 4; ++i) a[i] = *(const bf16x8*)&As[aoff[i]];
#pragma unroll
    for (int j = 0; j < 2; ++j) b[j] = *(const bf16x8*)&Bs[boff[j]];
#pragma unroll
    for (int i = 0; i < 4; ++i)
#pragma unroll
      for (int j = 0; j < 2; ++j)
        acc[i][j] = mfma16(a[i], b[j], acc[i][j]);
    __syncthreads();
  }

#pragma unroll
  for (int i = 0; i < 4; ++i) {
#pragma unroll
    for (int r = 0; r < 4; ++r) {
      int m = wr * 64 + i * 16 + fs * 4 + r;
      int grow = m0 + m;
      if (grow < Te) {
        int slot = lbase + grow;
        int tok = perm[slot];
        float s = scl[slot];
#pragma unroll
        for (int j = 0; j < 2; ++j) {
          int col = n0 + wc * 32 + j * 16 + fr;
          size_t oi = (size_t)tok * CDIM + col;
          float v = s * acc[i][j][r];
          if (init) out[oi] = v;
          else out[oi] += v;
        }
      }
    }
  }
}

extern "C" void kernel_launch(void* const* d_in, const int* in_sizes, int n_in,
                              void* d_out, int out_size, void* d_ws, size_t ws_size,
                              hipStream_t stream) {
  (void)in_sizes; (void)n_in; (void)out_size; (void)ws_size;
  const float* x   = (const float*)d_in[0];
  const float* gw  = (const float*)d_in[1];
  const float* w1  = (const float*)d_in[2];
  const float* w2  = (const float*)d_in[3];
  const float* w3  = (const float*)d_in[4];
  const float* sw1 = (const float*)d_in[5];
  const float* sw2 = (const float*)d_in[6];
  const float* sw3 = (const float*)d_in[7];
  float* out = (float*)d_out;

  char* p = (char*)d_ws;
  auto alloc = [&](size_t b) { char* r = p; p += (b + 255) & ~(size_t)255; return r; };
  u16*   xb      = (u16*)alloc((size_t)NTOK * CDIM * 2);
  u16*   wT1     = (u16*)alloc((size_t)HP * CDIM * 2);
  u16*   wT2     = (u16*)alloc((size_t)HP * CDIM * 2);
  u16*   wT3     = (u16*)alloc((size_t)CDIM * HP * 2);
  u16*   gbuf    = (u16*)alloc((size_t)NTOK * HP * 2);
  int*   idx_top = (int*)alloc((size_t)NTOK * 2 * 4);
  float* w_top   = (float*)alloc((size_t)NTOK * 2 * 4);
  float* probs   = (float*)alloc((size_t)NTOK * NEXP * 4);
  int*   perm    = (int*)alloc((size_t)NTOK * 3 * 4);
  float* scl     = (float*)alloc((size_t)NTOK * 3 * 4);
  int*   ctrl    = (int*)alloc(256);
  int*   counts  = ctrl;        // [0..8]
  int*   cursor  = ctrl + 12;   // [0..7]
  int*   offs    = ctrl + 20;   // [0..8]

  hipMemsetAsync(ctrl, 0, 256, stream);
  convert_x_kernel<<<NTOK * CDIM / 4 / 256, 256, 0, stream>>>(x, xb);
  router_kernel<<<NTOK / 4, 256, 0, stream>>>(x, gw, idx_top, w_top, probs,
                                              perm + 2 * NTOK, scl + 2 * NTOK);
  reduce_aux_kernel<<<1, 256, 0, stream>>>(probs, idx_top, counts, offs,
                                           out + (size_t)NTOK * CDIM);
  scatter_kernel<<<NTOK / 256, 256, 0, stream>>>(idx_top, w_top, offs, cursor, perm, scl);

  // shared expert first (init-writes every out element), then routed 0..7
  for (int ei = 0; ei < 9; ++ei) {
    int e = (ei == 0) ? NEXP : ei - 1;
    const float* a1 = (e == NEXP) ? sw1 : w1 + (size_t)e * CDIM * HDIM;
    const float* a2 = (e == NEXP) ? sw2 : w2 + (size_t)e * CDIM * HDIM;
    const float* a3 = (e == NEXP) ? sw3 : w3 + (size_t)e * HDIM * CDIM;
    convt_kernel<<<dim3(CDIM / 32, HP / 32), 256, 0, stream>>>(a1, wT1, CDIM, HDIM, CDIM, HP);
    convt_kernel<<<dim3(CDIM / 32, HP / 32), 256, 0, stream>>>(a2, wT2, CDIM, HDIM, CDIM, HP);
    convt_kernel<<<dim3(HP / 32, CDIM / 32), 256, 0, stream>>>(a3, wT3, HDIM, CDIM, HP, CDIM);
    gemm_h_kernel<<<dim3(NTOK / 128, HP / 64), 256, 0, stream>>>(
        xb, wT1, wT2, gbuf, perm, offs, counts, e);
    gemm_out_kernel<<<dim3(NTOK / 128, CDIM / 64), 256, 0, stream>>>(
        gbuf, wT3, out, perm, scl, offs, counts, e, (e == NEXP) ? 1 : 0);
  }
}

// Round 3
// 1078.373 us; speedup vs baseline: 2.4078x; 1.5655x over previous
//
#include <hip/hip_runtime.h>
#include <cstdint>
#include <cstddef>

#define NTOK 8192
#define CDIM 1024
#define NEXP 8
#define HDIM 2730
#define HP   2816
#define NLIST 9          // 8 routed + 1 shared
#define MAXTILE 200      // 64 shared + <=136 routed m-tiles

typedef unsigned short u16;
typedef __attribute__((ext_vector_type(4))) float f32x4;
typedef __attribute__((ext_vector_type(8))) __bf16 bf16x8;
typedef __attribute__((ext_vector_type(4))) unsigned short u16x4;

// meta layout (ints): [0..8]=list counts, [16..24]=list offsets into perm,
// [30]=ntiles, [32..231]=tile->list, [288..487]=tile->m0, [576..583]=scatter cursor
#define M_CNT 0
#define M_OFF 16
#define M_NT  30
#define M_TL  32
#define M_TM  288
#define M_CUR 576

static __device__ __forceinline__ u16 f2bf(float f) {
  __bf16 h = (__bf16)f;
  return __builtin_bit_cast(u16, h);
}

// 16B-per-lane async global->LDS. LDS dest is wave-uniform base + lane*16.
static __device__ __forceinline__ void async_cp16(const void* gsrc, void* ldst) {
  auto g = reinterpret_cast<const __attribute__((address_space(1))) unsigned int*>(
      reinterpret_cast<uintptr_t>(gsrc));
  auto l = reinterpret_cast<__attribute__((address_space(3))) unsigned int*>(
      static_cast<unsigned int>(reinterpret_cast<uintptr_t>(ldst)));
  __builtin_amdgcn_global_load_lds(g, l, 16, 0, 0);
}

static __device__ __forceinline__ f32x4 mfma16(bf16x8 a, bf16x8 b, f32x4 c) {
  return __builtin_amdgcn_mfma_f32_16x16x32_bf16(a, b, c, 0, 0, 0);
}

// ---------------- x fp32 -> bf16 ----------------
__global__ void convert_x_kernel(const float* __restrict__ x, u16* __restrict__ xb) {
  size_t i = (size_t)blockIdx.x * blockDim.x + threadIdx.x;
  f32x4 v = ((const f32x4*)x)[i];
  u16x4 o;
  o.x = f2bf(v.x); o.y = f2bf(v.y); o.z = f2bf(v.z); o.w = f2bf(v.w);
  ((u16x4*)xb)[i] = o;
}

// ---------------- router: wave per token, no atomics ----------------
__global__ void router_kernel(const float* __restrict__ x, const float* __restrict__ gw,
                              int* __restrict__ idx_top, float* __restrict__ w_top,
                              float* __restrict__ probs,
                              int* __restrict__ perm_sh, float* __restrict__ scl_sh) {
  __shared__ float gws[NEXP][CDIM];   // transposed: lane stride 4B, conflict-free
  for (int i = threadIdx.x; i < CDIM * NEXP; i += 256) {
    int c = i >> 3, e = i & 7;
    gws[e][c] = gw[i];
  }
  __syncthreads();
  const int lane = threadIdx.x & 63;
  const int wave = threadIdx.x >> 6;
  const int t = blockIdx.x * 4 + wave;
  float acc[NEXP];
#pragma unroll
  for (int e = 0; e < NEXP; ++e) acc[e] = 0.f;
  const float* xr = x + (size_t)t * CDIM;
#pragma unroll
  for (int u = 0; u < CDIM / 64; ++u) {
    float xv = xr[lane + 64 * u];
#pragma unroll
    for (int e = 0; e < NEXP; ++e) acc[e] = fmaf(xv, gws[e][lane + 64 * u], acc[e]);
  }
#pragma unroll
  for (int e = 0; e < NEXP; ++e) {
    float v = acc[e];
#pragma unroll
    for (int s = 32; s > 0; s >>= 1) v += __shfl_xor(v, s, 64);
    acc[e] = v;
  }
  if (lane == 0) {
    float mx = acc[0];
#pragma unroll
    for (int e = 1; e < NEXP; ++e) mx = fmaxf(mx, acc[e]);
    float p[NEXP], s = 0.f;
#pragma unroll
    for (int e = 0; e < NEXP; ++e) { p[e] = __expf(acc[e] - mx); s += p[e]; }
    float inv = 1.f / s;
#pragma unroll
    for (int e = 0; e < NEXP; ++e) { p[e] *= inv; probs[t * NEXP + e] = p[e]; }
    int i1 = 0;
#pragma unroll
    for (int e = 1; e < NEXP; ++e) if (p[e] > p[i1]) i1 = e;
    int i2 = (i1 == 0) ? 1 : 0;
#pragma unroll
    for (int e = 0; e < NEXP; ++e)
      if (e != i1 && e != i2 && p[e] > p[i2]) i2 = e;
    float wsum = p[i1] + p[i2];
    idx_top[t * 2] = i1; idx_top[t * 2 + 1] = i2;
    w_top[t * 2] = p[i1] / wsum; w_top[t * 2 + 1] = p[i2] / wsum;
    perm_sh[t] = t; scl_sh[t] = 1.0f;
  }
}

// -------- single-block: counts, offsets, aux loss, tile table --------
__global__ void reduce_aux_kernel(const float* __restrict__ probs,
                                  const int* __restrict__ idx_top,
                                  int* __restrict__ meta, float* __restrict__ aux_out) {
  __shared__ float sP[NEXP];
  __shared__ int sC[NEXP];
  if (threadIdx.x < NEXP) { sP[threadIdx.x] = 0.f; sC[threadIdx.x] = 0; }
  __syncthreads();
  float sp[NEXP];
  int cnt[NEXP];
#pragma unroll
  for (int e = 0; e < NEXP; ++e) { sp[e] = 0.f; cnt[e] = 0; }
  for (int t = threadIdx.x; t < NTOK; t += 256) {
    const float* pr = probs + (size_t)t * NEXP;
    int i1 = idx_top[2 * t], i2 = idx_top[2 * t + 1];
#pragma unroll
    for (int e = 0; e < NEXP; ++e) {
      sp[e] += pr[e];
      cnt[e] += (i1 == e) + (i2 == e);
    }
  }
#pragma unroll
  for (int e = 0; e < NEXP; ++e) {
    float v = sp[e]; int c = cnt[e];
#pragma unroll
    for (int s = 32; s > 0; s >>= 1) { v += __shfl_xor(v, s, 64); c += __shfl_xor(c, s, 64); }
    if ((threadIdx.x & 63) == 0) { atomicAdd(&sP[e], v); atomicAdd(&sC[e], c); }
  }
  __syncthreads();
  if (threadIdx.x == 0) {
    int o = 0; float aux = 0.f;
    for (int e = 0; e < NEXP; ++e) {
      meta[M_CNT + e] = sC[e];
      meta[M_OFF + e] = o; o += sC[e];
      aux += ((float)sC[e] / (float)NTOK) * (sP[e] / (float)NTOK);
    }
    meta[M_CNT + 8] = NTOK;        // shared list
    meta[M_OFF + 8] = 2 * NTOK;
    aux_out[0] = (float)NEXP * aux;
    int nt = 0;
    for (int l = 0; l < NLIST; ++l) {
      int c = meta[M_CNT + l];
      for (int m0 = 0; m0 < c && nt < MAXTILE; m0 += 128) {
        meta[M_TL + nt] = l;
        meta[M_TM + nt] = m0;
        ++nt;
      }
    }
    meta[M_NT] = nt;
  }
}

// ------ scatter: block-aggregated cursor atomics ------
__global__ void scatter_kernel(const int* __restrict__ idx_top, const float* __restrict__ w_top,
                               int* __restrict__ meta,
                               int* __restrict__ perm, float* __restrict__ scl) {
  __shared__ int lcnt[NEXP], lbase[NEXP], lcur[NEXP];
  if (threadIdx.x < NEXP) { lcnt[threadIdx.x] = 0; lcur[threadIdx.x] = 0; }
  __syncthreads();
  int t = blockIdx.x * 256 + threadIdx.x;
  int e0 = idx_top[2 * t], e1 = idx_top[2 * t + 1];
  atomicAdd(&lcnt[e0], 1);
  atomicAdd(&lcnt[e1], 1);
  __syncthreads();
  if (threadIdx.x < NEXP)
    lbase[threadIdx.x] = atomicAdd(&meta[M_CUR + threadIdx.x], lcnt[threadIdx.x]);
  __syncthreads();
  int p0 = atomicAdd(&lcur[e0], 1);
  int o0 = meta[M_OFF + e0] + lbase[e0] + p0;
  perm[o0] = t; scl[o0] = w_top[2 * t];
  int p1 = atomicAdd(&lcur[e1], 1);
  int o1 = meta[M_OFF + e1] + lbase[e1] + p1;
  perm[o1] = t; scl[o1] = w_top[2 * t + 1];
}

// ---- all-weight fp32->bf16 transpose+pad: 27 matrices, one launch ----
// type A (w1/w2-like): src [1024][2730] -> dst [2816][1024]
// type B (w3-like):    src [2730][1024] -> dst [1024][2816]
__global__ void convt_all_kernel(const float* __restrict__ w1, const float* __restrict__ w2,
                                 const float* __restrict__ w3, const float* __restrict__ sw1,
                                 const float* __restrict__ sw2, const float* __restrict__ sw3,
                                 u16* __restrict__ w1b, u16* __restrict__ w2b,
                                 u16* __restrict__ w3b) {
  const int z = blockIdx.y;
  const float* src;
  u16* dst;
  int K, M, Kp;
  if (z < 8)       { src = w1 + (size_t)z * CDIM * HDIM;        dst = w1b + (size_t)z * HP * CDIM; K = CDIM; M = HDIM; Kp = CDIM; }
  else if (z < 16) { src = w2 + (size_t)(z - 8) * CDIM * HDIM;  dst = w2b + (size_t)(z - 8) * HP * CDIM; K = CDIM; M = HDIM; Kp = CDIM; }
  else if (z < 24) { src = w3 + (size_t)(z - 16) * HDIM * CDIM; dst = w3b + (size_t)(z - 16) * CDIM * HP; K = HDIM; M = CDIM; Kp = HP; }
  else if (z == 24){ src = sw1; dst = w1b + (size_t)8 * HP * CDIM; K = CDIM; M = HDIM; Kp = CDIM; }
  else if (z == 25){ src = sw2; dst = w2b + (size_t)8 * HP * CDIM; K = CDIM; M = HDIM; Kp = CDIM; }
  else             { src = sw3; dst = w3b + (size_t)8 * CDIM * HP; K = HDIM; M = CDIM; Kp = HP; }
  int t = blockIdx.x;
  int tk, tm;
  if (K == CDIM) { tk = t & 31; tm = t >> 5; }   // 32 k-tiles x 88 m-tiles
  else           { tk = t >> 5; tm = t & 31; }   // 88 k-tiles x 32 m-tiles
  __shared__ float tile[32][33];
  int sk = tk * 32, sm = tm * 32;
  int tx = threadIdx.x & 31, ty = threadIdx.x >> 5;
#pragma unroll
  for (int i = 0; i < 4; ++i) {
    int k = sk + ty + i * 8, m = sm + tx;
    tile[ty + i * 8][tx] = (k < K && m < M) ? src[(size_t)k * M + m] : 0.f;
  }
  __syncthreads();
#pragma unroll
  for (int i = 0; i < 4; ++i) {
    int m = sm + ty + i * 8, k = sk + tx;
    dst[(size_t)m * Kp + k] = f2bf(tile[tx][ty + i * 8]);
  }
}

// ------- merged fused dual GEMM + SwiGLU over all lists -------
// BM=128, BN=64, BK=32; 4 waves 2x2; dual accumulators (w1,w2 share A and B-addr).
__global__ __launch_bounds__(256) void gemm_h_kernel(
    const u16* __restrict__ xb, const u16* __restrict__ w1b, const u16* __restrict__ w2b,
    u16* __restrict__ g, const int* __restrict__ perm, const int* __restrict__ meta) {
  const int bx = blockIdx.x;
  if (bx >= meta[M_NT]) return;
  const int l = meta[M_TL + bx];
  const int m0 = meta[M_TM + bx];
  const int Te = meta[M_CNT + l];
  const int lbase = meta[M_OFF + l];
  const int* pl = perm + lbase;
  const int n0 = blockIdx.y * 64;
  const u16* B1 = w1b + (size_t)l * HP * CDIM;
  const u16* B2 = w2b + (size_t)l * HP * CDIM;

  __shared__ __align__(16) u16 As[128 * 32];
  __shared__ __align__(16) u16 Bs1[64 * 32];
  __shared__ __align__(16) u16 Bs2[64 * 32];

  const int lane = threadIdx.x & 63;
  const int wave = threadIdx.x >> 6;
  const int wr = wave >> 1, wc = wave & 1;
  const int sr = lane >> 2;
  // XOR-swizzled source chunk: LDS slot (row, cs) holds global chunk cs^((row>>1)&3)
  const int scx = ((lane & 3) ^ ((sr >> 1) & 3)) * 8;

  int r0 = m0 + wave * 16 + sr;      if (r0 >= Te) r0 = Te - 1;
  int r1 = m0 + 64 + wave * 16 + sr; if (r1 >= Te) r1 = Te - 1;
  const u16* ga0 = xb + (size_t)pl[r0] * CDIM + scx;
  const u16* ga1 = xb + (size_t)pl[r1] * CDIM + scx;
  const u16* gb1 = B1 + (size_t)(n0 + wave * 16 + sr) * CDIM + scx;
  const u16* gb2 = B2 + (size_t)(n0 + wave * 16 + sr) * CDIM + scx;
  u16* la0 = &As[(wave * 16) * 32];
  u16* la1 = &As[(64 + wave * 16) * 32];
  u16* lb1 = &Bs1[(wave * 16) * 32];
  u16* lb2 = &Bs2[(wave * 16) * 32];

  const int fr = lane & 15, fs = lane >> 4;
  const int fsx = (fs ^ ((fr >> 1) & 3)) * 8;   // swizzled read chunk
  int aoff[4], boff[2];
#pragma unroll
  for (int i = 0; i < 4; ++i) aoff[i] = (wr * 64 + i * 16 + fr) * 32 + fsx;
#pragma unroll
  for (int j = 0; j < 2; ++j) boff[j] = (wc * 32 + j * 16 + fr) * 32 + fsx;

  f32x4 acc1[4][2] = {};
  f32x4 acc2[4][2] = {};

  for (int k0 = 0; k0 < CDIM; k0 += 32) {
    async_cp16(ga0, la0);
    async_cp16(ga1, la1);
    async_cp16(gb1, lb1);
    async_cp16(gb2, lb2);
    ga0 += 32; ga1 += 32; gb1 += 32; gb2 += 32;
    __syncthreads();
    bf16x8 a[4], b1[2], b2[2];
#pragma unroll
    for (int i = 0; i < 4; ++i) a[i] = *(const bf16x8*)&As[aoff[i]];
#pragma unroll
    for (int j = 0; j < 2; ++j) {
      b1[j] = *(const bf16x8*)&Bs1[boff[j]];
      b2[j] = *(const bf16x8*)&Bs2[boff[j]];
    }
#pragma unroll
    for (int i = 0; i < 4; ++i)
#pragma unroll
      for (int j = 0; j < 2; ++j) {
        acc1[i][j] = mfma16(a[i], b1[j], acc1[i][j]);
        acc2[i][j] = mfma16(a[i], b2[j], acc2[i][j]);
      }
    __syncthreads();
  }

  // epilogue: silu(h1)*h2 -> bf16 g rows (lbase+m0+m). C/D: col=lane&15, row=quad*4+reg.
#pragma unroll
  for (int i = 0; i < 4; ++i)
#pragma unroll
    for (int j = 0; j < 2; ++j)
#pragma unroll
      for (int r = 0; r < 4; ++r) {
        int m = wr * 64 + i * 16 + fs * 4 + r;
        if (m0 + m < Te) {
          int col = n0 + wc * 32 + j * 16 + fr;
          float h1 = acc1[i][j][r];
          float h2 = acc2[i][j][r];
          float gv = h1 / (1.f + __expf(-h1)) * h2;
          g[(size_t)(lbase + m0 + m) * HP + col] = f2bf(gv);
        }
      }
}

// ------- merged GEMM: y = g @ w3, atomically scatter s*y into out -------
// BM=128, BN=128, BK=32; 4 waves 2x2, each 64x64.
__global__ __launch_bounds__(256) void gemm_out_kernel(
    const u16* __restrict__ g, const u16* __restrict__ w3b, float* __restrict__ out,
    const int* __restrict__ perm, const float* __restrict__ scl,
    const int* __restrict__ meta) {
  const int bx = blockIdx.x;
  if (bx >= meta[M_NT]) return;
  const int l = meta[M_TL + bx];
  const int m0 = meta[M_TM + bx];
  const int Te = meta[M_CNT + l];
  const int lbase = meta[M_OFF + l];
  const int n0 = blockIdx.y * 128;
  const u16* B3 = w3b + (size_t)l * CDIM * HP;

  __shared__ __align__(16) u16 As[128 * 32];
  __shared__ __align__(16) u16 Bs[128 * 32];

  const int lane = threadIdx.x & 63;
  const int wave = threadIdx.x >> 6;
  const int wr = wave >> 1, wc = wave & 1;
  const int sr = lane >> 2;
  const int scx = ((lane & 3) ^ ((sr >> 1) & 3)) * 8;

  // tail rows read garbage from the next list's region (in-bounds); results discarded.
  const u16* ga0 = g + (size_t)(lbase + m0 + wave * 16 + sr) * HP + scx;
  const u16* ga1 = g + (size_t)(lbase + m0 + 64 + wave * 16 + sr) * HP + scx;
  const u16* gb0 = B3 + (size_t)(n0 + wave * 16 + sr) * HP + scx;
  const u16* gb1 = B3 + (size_t)(n0 + 64 + wave * 16 + sr) * HP + scx;
  u16* la0 = &As[(wave * 16) * 32];
  u16* la1 = &As[(64 + wave * 16) * 32];
  u16* lb0 = &Bs[(wave * 16) * 32];
  u16* lb1 = &Bs[(64 + wave * 16) * 32];

  const int fr = lane & 15, fs = lane >> 4;
  const int fsx = (fs ^ ((fr >> 1) & 3)) * 8;
  int aoff[4], boff[4];
#pragma unroll
  for (int i = 0; i < 4; ++i) aoff[i] = (wr * 64 + i * 16 + fr) * 32 + fsx;
#pragma unroll
  for (int j = 0; j < 4; ++j) boff[j] = (wc * 64 + j * 16 + fr) * 32 + fsx;

  f32x4 acc[4][4] = {};

  for (int k0 = 0; k0 < HP; k0 += 32) {
    async_cp16(ga0, la0);
    async_cp16(ga1, la1);
    async_cp16(gb0, lb0);
    async_cp16(gb1, lb1);
    ga0 += 32; ga1 += 32; gb0 += 32; gb1 += 32;
    __syncthreads();
    bf16x8 a[4], b[4];
#pragma unroll
    for (int i = 0; i < 4; ++i) a[i] = *(const bf16x8*)&As[aoff[i]];
#pragma unroll
    for (int j = 0; j < 4; ++j) b[j] = *(const bf16x8*)&Bs[boff[j]];
#pragma unroll
    for (int i = 0; i < 4; ++i)
#pragma unroll
      for (int j = 0; j < 4; ++j)
        acc[i][j] = mfma16(a[i], b[j], acc[i][j]);
    __syncthreads();
  }

#pragma unroll
  for (int i = 0; i < 4; ++i) {
#pragma unroll
    for (int r = 0; r < 4; ++r) {
      int m = wr * 64 + i * 16 + fs * 4 + r;
      int grow = m0 + m;
      if (grow < Te) {
        int slot = lbase + grow;
        int tok = perm[slot];
        float s = scl[slot];
#pragma unroll
        for (int j = 0; j < 4; ++j) {
          int col = n0 + wc * 64 + j * 16 + fr;
          atomicAdd(&out[(size_t)tok * CDIM + col], s * acc[i][j][r]);
        }
      }
    }
  }
}

extern "C" void kernel_launch(void* const* d_in, const int* in_sizes, int n_in,
                              void* d_out, int out_size, void* d_ws, size_t ws_size,
                              hipStream_t stream) {
  (void)in_sizes; (void)n_in; (void)out_size; (void)ws_size;
  const float* x   = (const float*)d_in[0];
  const float* gw  = (const float*)d_in[1];
  const float* w1  = (const float*)d_in[2];
  const float* w2  = (const float*)d_in[3];
  const float* w3  = (const float*)d_in[4];
  const float* sw1 = (const float*)d_in[5];
  const float* sw2 = (const float*)d_in[6];
  const float* sw3 = (const float*)d_in[7];
  float* out = (float*)d_out;

  char* p = (char*)d_ws;
  auto alloc = [&](size_t b) { char* r = p; p += (b + 255) & ~(size_t)255; return r; };
  u16*   xb      = (u16*)alloc((size_t)NTOK * CDIM * 2);
  u16*   w1b     = (u16*)alloc((size_t)NLIST * HP * CDIM * 2);
  u16*   w2b     = (u16*)alloc((size_t)NLIST * HP * CDIM * 2);
  u16*   w3b     = (u16*)alloc((size_t)NLIST * CDIM * HP * 2);
  u16*   gbuf    = (u16*)alloc((size_t)3 * NTOK * HP * 2);
  int*   idx_top = (int*)alloc((size_t)NTOK * 2 * 4);
  float* w_top   = (float*)alloc((size_t)NTOK * 2 * 4);
  float* probs   = (float*)alloc((size_t)NTOK * NEXP * 4);
  int*   perm    = (int*)alloc((size_t)NTOK * 3 * 4);
  float* scl     = (float*)alloc((size_t)NTOK * 3 * 4);
  int*   meta    = (int*)alloc(4096);

  hipMemsetAsync(out, 0, ((size_t)NTOK * CDIM + 1) * 4, stream);
  hipMemsetAsync(meta, 0, 4096, stream);
  convert_x_kernel<<<NTOK * CDIM / 4 / 256, 256, 0, stream>>>(x, xb);
  router_kernel<<<NTOK / 4, 256, 0, stream>>>(x, gw, idx_top, w_top, probs,
                                              perm + 2 * NTOK, scl + 2 * NTOK);
  reduce_aux_kernel<<<1, 256, 0, stream>>>(probs, idx_top, meta,
                                           out + (size_t)NTOK * CDIM);
  scatter_kernel<<<NTOK / 256, 256, 0, stream>>>(idx_top, w_top, meta, perm, scl);
  convt_all_kernel<<<dim3(2816, 27), 256, 0, stream>>>(w1, w2, w3, sw1, sw2, sw3,
                                                       w1b, w2b, w3b);
  gemm_h_kernel<<<dim3(MAXTILE, HP / 64), 256, 0, stream>>>(
      xb, w1b, w2b, gbuf, perm, meta);
  gemm_out_kernel<<<dim3(MAXTILE, CDIM / 128), 256, 0, stream>>>(
      gbuf, w3b, out, perm, scl, meta);
}